// Round 18
// baseline (159.172 us; speedup 1.0000x reference)
//
#include <hip/hip_runtime.h>
#include <hip/hip_bf16.h>
#include <cstdint>
#include <math.h>

#define BB 256
#define CC 64
#define TT 4000
#define NHID 64
#define NOUT 64
#define NMLP (NOUT*(CC+1))  // 4160
#define TCH 128             // t per k_apply block

typedef __attribute__((ext_vector_type(8))) short short8v;      // 8 fp16 = 4 VGPR
typedef __attribute__((ext_vector_type(4))) float f32x4;        // MFMA C/D frag + NT loads
typedef __attribute__((ext_vector_type(2))) __fp16 half2v;      // cvt_pkrtz result

// ---------------- K1: fused per-channel log-variance + MLP hypernetwork ----------------
// grid 256 (one block per sample b), block 1024. 16 threads per channel row.
// Produces wsB[b][o] (fp32) and wtg[b][o][c] (fp16, natural layout for A-frags).
__global__ __launch_bounds__(1024) void k_feat(const float* __restrict__ x,
                                               const float* __restrict__ W1,
                                               const float* __restrict__ b1,
                                               const float* __restrict__ W2,
                                               const float* __restrict__ b2,
                                               unsigned short* __restrict__ wtg,
                                               float* __restrict__ wsB) {
    int b   = blockIdx.x;
    int tid = threadIdx.x;
    int c   = tid >> 4;      // 0..63
    int sub = tid & 15;      // 0..15

    const float4* row = (const float4*)(x + (size_t)b * (CC * TT) + (size_t)c * TT);
    float s = 0.f, ss = 0.f;
    #pragma unroll 4
    for (int i = sub; i < TT / 4; i += 16) {   // 1000 float4 per row / 16 threads
        float4 v = row[i];
        s  += v.x + v.y + v.z + v.w;
        ss += v.x * v.x + v.y * v.y + v.z * v.z + v.w * v.w;
    }
    #pragma unroll
    for (int off = 8; off > 0; off >>= 1) {
        s  += __shfl_xor(s, off);
        ss += __shfl_xor(ss, off);
    }

    __shared__ float fs[CC];
    __shared__ float hs[NHID];
    if (sub == 0) {
        float var = (ss - s * s / (float)TT) / (float)(TT - 1);
        float f = logf(var);
        if (isinf(f) && f < 0.f) f = 0.f;   // jnp.where(isneginf, 0, .)
        fs[c] = f;
    }
    __syncthreads();

    if (tid < NHID) {
        float v = b1[tid];
        #pragma unroll 8
        for (int k = 0; k < CC; ++k) v = fmaf(fs[k], W1[k * NHID + tid], v);
        hs[tid] = v > 0.f ? v : 0.f;
    }
    __syncthreads();

    for (int j = tid; j < NMLP; j += 1024) {
        float v = b2[j];
        #pragma unroll 8
        for (int k = 0; k < NHID; ++k) v = fmaf(hs[k], W2[k * NMLP + j], v);
        if (j < NOUT) {
            wsB[b * NOUT + j] = v;
        } else {
            // mlp_out[64 + o*64 + c] = W[o][c] -> natural [o][c] fp16 (RTN)
            _Float16 hf = (_Float16)v;
            wtg[(size_t)b * 4096 + (j - NOUT)] = *(unsigned short*)&hf;
        }
    }
}

// ---------------- K2 (MFMA fp16): out[b,o,t] = sum_c W[o,c]*x[b,c,t] + bias[o] ----------------
// grid (32, 256), block 256 (4 waves). t-chunks processed in REVERSE order
// (LIFO vs k_feat's forward read -> L3 recency hits), x loaded non-temporally
// (read-once; don't evict k_feat leftovers). Stage fp32 -> fp16 (v_cvt_pkrtz)
// -> LDS [t][c] (16 KB, XOR swizzle); 16 mfma_f32_16x16x32_f16/wave;
// epilogue LDS transpose -> full-line f32x4 NT stores. 32 KB LDS.
__global__ __launch_bounds__(256, 4) void k_apply(const float* __restrict__ x,
                                                  const unsigned short* __restrict__ wtg,
                                                  const float* __restrict__ wsB,
                                                  float* __restrict__ out) {
    int b   = (BB - 1) - blockIdx.y;
    int tb  = (31 - blockIdx.x) * TCH;  // REVERSED: freshest-in-L3 chunks first
    int tid = threadIdx.x;
    int l   = tid & 63, w = tid >> 6;

    __shared__ __align__(16) char ldsb[TCH * CC * 4];     // 32 KB
    float* ot = (float*)ldsb;                             // epilogue: 64x128 fp32

    // ---- staging: thread owns c-octet (cslot) x t-quad (f4) ----
    int cslot = tid & 7;                 // c = cslot*8 + p
    int f4    = tid >> 3;                // t-quad 0..31
    int maxf4 = ((TT - tb) >> 2) - 1;    // 7 on tail chunk only
    int f4c   = f4 <= maxf4 ? f4 : maxf4;
    const float* xb = x + (size_t)b * (CC * TT) + tb + f4c * 4;

    f32x4 xr[8];
    #pragma unroll
    for (int p = 0; p < 8; ++p)
        xr[p] = __builtin_nontemporal_load(
                    (const f32x4*)(xb + (size_t)(cslot * 8 + p) * TT));

    // convert each row-quad to 4 packed fp16 (RTZ; err ~2^-11 rel, fine vs thr)
    uint2 h4[8];
    #pragma unroll
    for (int p = 0; p < 8; ++p) {
        half2v p0 = __builtin_amdgcn_cvt_pkrtz(xr[p][0], xr[p][1]);
        half2v p1 = __builtin_amdgcn_cvt_pkrtz(xr[p][2], xr[p][3]);
        h4[p].x = *(unsigned*)&p0;
        h4[p].y = *(unsigned*)&p1;
    }
    #pragma unroll
    for (int j = 0; j < 4; ++j) {
        int t = f4 * 4 + j;
        short8v hv;
        #pragma unroll
        for (int p = 0; p < 8; ++p) {
            unsigned word = (j < 2) ? h4[p].x : h4[p].y;
            hv[p] = (short)((j & 1) ? (word >> 16) : (word & 0xFFFFu));
        }
        int byteoff = t * 128 + ((cslot * 16) ^ ((t & 7) << 4));    // XOR swizzle
        *(short8v*)(ldsb + byteoff) = hv;
    }
    __syncthreads();

    // ---- A-fragments (W fp16) straight from global (L2-hot; 16B/lane) ----
    const unsigned short* wb = wtg + (size_t)b * 4096;
    short8v af[4][2];
    #pragma unroll
    for (int mi = 0; mi < 4; ++mi)
        #pragma unroll
        for (int kc = 0; kc < 2; ++kc)
            af[mi][kc] = *(const short8v*)(wb + (mi * 16 + (l & 15)) * 64
                                              + kc * 32 + (l >> 4) * 8);

    // ---- acc init from bias: D row o = (l>>4)*4 + r ----
    f32x4 acc[4][2];
    #pragma unroll
    for (int mi = 0; mi < 4; ++mi) {
        float4 bv = *(const float4*)(wsB + b * 64 + mi * 16 + (l >> 4) * 4);
        #pragma unroll
        for (int ti = 0; ti < 2; ++ti) {
            acc[mi][ti][0] = bv.x; acc[mi][ti][1] = bv.y;
            acc[mi][ti][2] = bv.z; acc[mi][ti][3] = bv.w;
        }
    }

    // ---- MFMA main: per t-tile read 2 B-frags, run 8 MFMAs ----
    #pragma unroll
    for (int ti = 0; ti < 2; ++ti) {
        int tl = w * 32 + ti * 16 + (l & 15);         // t row in LDS
        int rowbase = tl * 128;
        int sw = (tl & 7) << 4;
        short8v bf[2];
        #pragma unroll
        for (int kc = 0; kc < 2; ++kc) {
            int boff = rowbase + ((kc * 64 + (l >> 4) * 16) ^ sw);
            bf[kc] = *(const short8v*)(ldsb + boff);
        }
        #pragma unroll
        for (int mi = 0; mi < 4; ++mi)
            #pragma unroll
            for (int kc = 0; kc < 2; ++kc)
                acc[mi][ti] = __builtin_amdgcn_mfma_f32_16x16x32_f16(
                                  af[mi][kc], bf[kc], acc[mi][ti], 0, 0, 0);
    }

    // ---- epilogue: transpose via LDS (reuse buffer) then full-line NT stores ----
    __syncthreads();                     // all B-frag reads done; buffer reusable

    #pragma unroll
    for (int mi = 0; mi < 4; ++mi)
        #pragma unroll
        for (int ti = 0; ti < 2; ++ti) {
            int t = w * 32 + ti * 16 + (l & 15);
            #pragma unroll
            for (int r = 0; r < 4; ++r) {
                int o = mi * 16 + (l >> 4) * 4 + r;
                ot[o * 128 + (t ^ ((o & 7) << 2))] = acc[mi][ti][r];  // 2-way (free)
            }
        }
    __syncthreads();

    // read back row-major, 16B/lane, 8 consecutive lanes per o-row
    // (128B contiguous per row per instr = full line -> NT safe)
    int ro = tid >> 3;                   // 0..31 (two o-passes)
    int q0 = tid & 7;                    // quad slot within row
    #pragma unroll
    for (int k2 = 0; k2 < 2; ++k2) {
        int o = ro + k2 * 32;
        int sw2 = (o & 7) << 2;
        float* op = out + (size_t)b * (NOUT * TT) + (size_t)o * TT + tb;
        #pragma unroll
        for (int kq = 0; kq < 4; ++kq) {
            int t0 = (q0 + kq * 8) * 4;
            if (tb + t0 < TT) {
                f32x4 v = *(const f32x4*)&ot[o * 128 + (t0 ^ sw2)];
                __builtin_nontemporal_store(v, (f32x4*)(op + t0));
            }
        }
    }
}

extern "C" void kernel_launch(void* const* d_in, const int* in_sizes, int n_in,
                              void* d_out, int out_size, void* d_ws, size_t ws_size,
                              hipStream_t stream) {
    const float* x  = (const float*)d_in[0];
    const float* W1 = (const float*)d_in[1];
    const float* b1 = (const float*)d_in[2];
    const float* W2 = (const float*)d_in[3];
    const float* b2 = (const float*)d_in[4];
    float* out = (float*)d_out;
    float* ws  = (float*)d_ws;

    float*          wsB = ws;                               // 256*64 fp32
    unsigned short* wtg = (unsigned short*)(ws + 16384);    // 256*4096 fp16 (2 MB)

    k_feat<<<256, 1024, 0, stream>>>(x, W1, b1, W2, b2, wtg, wsB);
    k_apply<<<dim3(32, 256), 256, 0, stream>>>(x, wtg, wsB, out);
}

// Round 19
// 144.623 us; speedup vs baseline: 1.1006x; 1.1006x over previous
//
#include <hip/hip_runtime.h>
#include <hip/hip_bf16.h>
#include <cstdint>
#include <math.h>

#define BB 256
#define CC 64
#define TT 4000
#define NHID 64
#define NOUT 64
#define NMLP (NOUT*(CC+1))  // 4160
#define TCH 128             // t per k_apply block

typedef __attribute__((ext_vector_type(8))) short short8v;      // 8 fp16 = 4 VGPR
typedef __attribute__((ext_vector_type(4))) float f32x4;        // MFMA C/D frag
typedef __attribute__((ext_vector_type(2))) __fp16 half2v;      // cvt_pkrtz result

// ---------------- K1: fused per-channel log-variance + MLP hypernetwork ----------------
// grid 256 (one block per sample b), block 1024. 16 threads per channel row.
// Produces wsB[b][o] (fp32) and wtg[b][o][c] (fp16, natural layout for A-frags).
__global__ __launch_bounds__(1024) void k_feat(const float* __restrict__ x,
                                               const float* __restrict__ W1,
                                               const float* __restrict__ b1,
                                               const float* __restrict__ W2,
                                               const float* __restrict__ b2,
                                               unsigned short* __restrict__ wtg,
                                               float* __restrict__ wsB) {
    int b   = blockIdx.x;
    int tid = threadIdx.x;
    int c   = tid >> 4;      // 0..63
    int sub = tid & 15;      // 0..15

    const float4* row = (const float4*)(x + (size_t)b * (CC * TT) + (size_t)c * TT);
    float s = 0.f, ss = 0.f;
    #pragma unroll 4
    for (int i = sub; i < TT / 4; i += 16) {   // 1000 float4 per row / 16 threads
        float4 v = row[i];
        s  += v.x + v.y + v.z + v.w;
        ss += v.x * v.x + v.y * v.y + v.z * v.z + v.w * v.w;
    }
    #pragma unroll
    for (int off = 8; off > 0; off >>= 1) {
        s  += __shfl_xor(s, off);
        ss += __shfl_xor(ss, off);
    }

    __shared__ float fs[CC];
    __shared__ float hs[NHID];
    if (sub == 0) {
        float var = (ss - s * s / (float)TT) / (float)(TT - 1);
        float f = logf(var);
        if (isinf(f) && f < 0.f) f = 0.f;   // jnp.where(isneginf, 0, .)
        fs[c] = f;
    }
    __syncthreads();

    if (tid < NHID) {
        float v = b1[tid];
        #pragma unroll 8
        for (int k = 0; k < CC; ++k) v = fmaf(fs[k], W1[k * NHID + tid], v);
        hs[tid] = v > 0.f ? v : 0.f;
    }
    __syncthreads();

    for (int j = tid; j < NMLP; j += 1024) {
        float v = b2[j];
        #pragma unroll 8
        for (int k = 0; k < NHID; ++k) v = fmaf(hs[k], W2[k * NMLP + j], v);
        if (j < NOUT) {
            wsB[b * NOUT + j] = v;
        } else {
            // mlp_out[64 + o*64 + c] = W[o][c] -> natural [o][c] fp16 (RTN)
            _Float16 hf = (_Float16)v;
            wtg[(size_t)b * 4096 + (j - NOUT)] = *(unsigned short*)&hf;
        }
    }
}

// ---------------- K2 (MFMA fp16): out[b,o,t] = sum_c W[o,c]*x[b,c,t] + bias[o] ----------------
// grid (32, 256), block 256 (4 waves). t-chunks processed in REVERSE order
// (LIFO vs k_feat's forward read -> L3 recency hits); x loads NORMAL (R18
// lesson: nt loads bypass the L3 probe and cost ~+11 us). Stage fp32 -> fp16
// (v_cvt_pkrtz) -> LDS [t][c] (16 KB, XOR swizzle); 16 mfma/wave; epilogue
// LDS transpose -> full-line f32x4 NT stores. 32 KB LDS -> 5 blocks/CU.
__global__ __launch_bounds__(256, 4) void k_apply(const float* __restrict__ x,
                                                  const unsigned short* __restrict__ wtg,
                                                  const float* __restrict__ wsB,
                                                  float* __restrict__ out) {
    int b   = (BB - 1) - blockIdx.y;
    int tb  = (31 - blockIdx.x) * TCH;  // REVERSED: freshest-in-L3 chunks first
    int tid = threadIdx.x;
    int l   = tid & 63, w = tid >> 6;

    __shared__ __align__(16) char ldsb[TCH * CC * 4];     // 32 KB
    float* ot = (float*)ldsb;                             // epilogue: 64x128 fp32

    // ---- staging: thread owns c-octet (cslot) x t-quad (f4) ----
    int cslot = tid & 7;                 // c = cslot*8 + p
    int f4    = tid >> 3;                // t-quad 0..31
    int maxf4 = ((TT - tb) >> 2) - 1;    // 7 on tail chunk only
    int f4c   = f4 <= maxf4 ? f4 : maxf4;
    const float* xb = x + (size_t)b * (CC * TT) + tb + f4c * 4;

    float4 xr[8];
    #pragma unroll
    for (int p = 0; p < 8; ++p)
        xr[p] = *(const float4*)(xb + (size_t)(cslot * 8 + p) * TT);

    // convert each row-quad to 4 packed fp16 (RTZ; err ~2^-11 rel, fine vs thr)
    uint2 h4[8];
    #pragma unroll
    for (int p = 0; p < 8; ++p) {
        half2v p0 = __builtin_amdgcn_cvt_pkrtz(xr[p].x, xr[p].y);
        half2v p1 = __builtin_amdgcn_cvt_pkrtz(xr[p].z, xr[p].w);
        h4[p].x = *(unsigned*)&p0;
        h4[p].y = *(unsigned*)&p1;
    }
    #pragma unroll
    for (int j = 0; j < 4; ++j) {
        int t = f4 * 4 + j;
        short8v hv;
        #pragma unroll
        for (int p = 0; p < 8; ++p) {
            unsigned word = (j < 2) ? h4[p].x : h4[p].y;
            hv[p] = (short)((j & 1) ? (word >> 16) : (word & 0xFFFFu));
        }
        int byteoff = t * 128 + ((cslot * 16) ^ ((t & 7) << 4));    // XOR swizzle
        *(short8v*)(ldsb + byteoff) = hv;
    }
    __syncthreads();

    // ---- A-fragments (W fp16) straight from global (L2-hot; 16B/lane) ----
    const unsigned short* wb = wtg + (size_t)b * 4096;
    short8v af[4][2];
    #pragma unroll
    for (int mi = 0; mi < 4; ++mi)
        #pragma unroll
        for (int kc = 0; kc < 2; ++kc)
            af[mi][kc] = *(const short8v*)(wb + (mi * 16 + (l & 15)) * 64
                                              + kc * 32 + (l >> 4) * 8);

    // ---- acc init from bias: D row o = (l>>4)*4 + r ----
    f32x4 acc[4][2];
    #pragma unroll
    for (int mi = 0; mi < 4; ++mi) {
        float4 bv = *(const float4*)(wsB + b * 64 + mi * 16 + (l >> 4) * 4);
        #pragma unroll
        for (int ti = 0; ti < 2; ++ti) {
            acc[mi][ti][0] = bv.x; acc[mi][ti][1] = bv.y;
            acc[mi][ti][2] = bv.z; acc[mi][ti][3] = bv.w;
        }
    }

    // ---- MFMA main: per t-tile read 2 B-frags, run 8 MFMAs ----
    #pragma unroll
    for (int ti = 0; ti < 2; ++ti) {
        int tl = w * 32 + ti * 16 + (l & 15);         // t row in LDS
        int rowbase = tl * 128;
        int sw = (tl & 7) << 4;
        short8v bf[2];
        #pragma unroll
        for (int kc = 0; kc < 2; ++kc) {
            int boff = rowbase + ((kc * 64 + (l >> 4) * 16) ^ sw);
            bf[kc] = *(const short8v*)(ldsb + boff);
        }
        #pragma unroll
        for (int mi = 0; mi < 4; ++mi)
            #pragma unroll
            for (int kc = 0; kc < 2; ++kc)
                acc[mi][ti] = __builtin_amdgcn_mfma_f32_16x16x32_f16(
                                  af[mi][kc], bf[kc], acc[mi][ti], 0, 0, 0);
    }

    // ---- epilogue: transpose via LDS (reuse buffer) then full-line NT stores ----
    __syncthreads();                     // all B-frag reads done; buffer reusable

    #pragma unroll
    for (int mi = 0; mi < 4; ++mi)
        #pragma unroll
        for (int ti = 0; ti < 2; ++ti) {
            int t = w * 32 + ti * 16 + (l & 15);
            #pragma unroll
            for (int r = 0; r < 4; ++r) {
                int o = mi * 16 + (l >> 4) * 4 + r;
                ot[o * 128 + (t ^ ((o & 7) << 2))] = acc[mi][ti][r];  // 2-way (free)
            }
        }
    __syncthreads();

    // read back row-major, 16B/lane, 8 consecutive lanes per o-row
    // (128B contiguous per row per instr = full line -> NT safe)
    int ro = tid >> 3;                   // 0..31 (two o-passes)
    int q0 = tid & 7;                    // quad slot within row
    #pragma unroll
    for (int k2 = 0; k2 < 2; ++k2) {
        int o = ro + k2 * 32;
        int sw2 = (o & 7) << 2;
        float* op = out + (size_t)b * (NOUT * TT) + (size_t)o * TT + tb;
        #pragma unroll
        for (int kq = 0; kq < 4; ++kq) {
            int t0 = (q0 + kq * 8) * 4;
            if (tb + t0 < TT) {
                f32x4 v = *(const f32x4*)&ot[o * 128 + (t0 ^ sw2)];
                __builtin_nontemporal_store(v, (f32x4*)(op + t0));
            }
        }
    }
}

extern "C" void kernel_launch(void* const* d_in, const int* in_sizes, int n_in,
                              void* d_out, int out_size, void* d_ws, size_t ws_size,
                              hipStream_t stream) {
    const float* x  = (const float*)d_in[0];
    const float* W1 = (const float*)d_in[1];
    const float* b1 = (const float*)d_in[2];
    const float* W2 = (const float*)d_in[3];
    const float* b2 = (const float*)d_in[4];
    float* out = (float*)d_out;
    float* ws  = (float*)d_ws;

    float*          wsB = ws;                               // 256*64 fp32
    unsigned short* wtg = (unsigned short*)(ws + 16384);    // 256*4096 fp16 (2 MB)

    k_feat<<<256, 1024, 0, stream>>>(x, W1, b1, W2, b2, wtg, wsB);
    k_apply<<<dim3(32, 256), 256, 0, stream>>>(x, wtg, wsB, out);
}